// Round 9
// baseline (134.800 us; speedup 1.0000x reference)
//
#include <hip/hip_runtime.h>
#include <math.h>

typedef __bf16 v8bf __attribute__((ext_vector_type(8)));
typedef __bf16 v4bf __attribute__((ext_vector_type(4)));
typedef float  v4f  __attribute__((ext_vector_type(4)));

constexpr int Bsz  = 8;
constexpr int Cch  = 32;
constexpr int WIMG = 128;
constexpr int OH   = 64;
constexpr int OW   = 64;
constexpr int INCH = 201;
constexpr int KP   = 224;
constexpr int NK   = 7;
constexpr int OUTCH = 1152;
constexpr int MTOT = Bsz * OH * OW;   // 32768
constexpr float BN_EPS = 1e-5f;

// ws layout
constexpr size_t WT_BYTES = (size_t)NK * OUTCH * 32 * 2;   // 516,096
constexpr size_t BIAS_OFF = WT_BYTES;
constexpr size_t FEAT_OFF = BIAS_OFF + OUTCH * 4;          // 520,704 (16-aligned)

// ---- async global->LDS (wave-uniform base + lane*16 contiguous) ----
typedef const void __attribute__((address_space(1)))* gas_ptr;
typedef void __attribute__((address_space(3)))* las_ptr;
__device__ __forceinline__ void load16_lds(const void* g, void* l) {
    __builtin_amdgcn_global_load_lds((gas_ptr)(uintptr_t)g, (las_ptr)(uintptr_t)l, 16, 0, 0);
}

// ---------------------------------------------------------------------------
// K1: prep (own kernel, zero LDS). BN-fold, bf16, transpose, k-tile.
// ---------------------------------------------------------------------------
constexpr int NPREP = OUTCH * KP + OUTCH;    // 259,200
constexpr int PREP_BLOCKS = (NPREP + 255) / 256;

__global__ __launch_bounds__(256)
void prep_kernel(const float* __restrict__ conv_w,
                 const float* __restrict__ gamma,
                 const float* __restrict__ beta,
                 const float* __restrict__ mean,
                 const float* __restrict__ var,
                 __bf16* __restrict__ Wt,
                 float* __restrict__ biasp) {
    int idx = blockIdx.x * blockDim.x + threadIdx.x;
    const int nW = OUTCH * KP;
    if (idx < nW) {
        int o = idx / KP;
        int f = idx - o * KP;
        float inv = gamma[o] * rsqrtf(var[o] + BN_EPS);
        float v = (f < INCH) ? conv_w[o * INCH + f] * inv : 0.0f;
        Wt[((size_t)(f >> 5) * OUTCH + o) * 32 + (f & 31)] = (__bf16)v;
    } else if (idx < nW + OUTCH) {
        int o = idx - nW;
        float inv = gamma[o] * rsqrtf(var[o] + BN_EPS);
        biasp[o] = beta[o] - mean[o] * inv;
    }
}

// ---------------------------------------------------------------------------
// K2: feat (R7/R8-validated bf16 version). One block per (b,ho).
// ---------------------------------------------------------------------------
constexpr int SXB = 132;            // sx row stride (bf16 elems)
constexpr int FEAT_BLOCKS = Bsz * OH;        // 512

__global__ __launch_bounds__(256)
void feat_kernel(const float* __restrict__ x, __bf16* __restrict__ feat) {
    __shared__ __align__(16) __bf16 sx[Cch * 3 * SXB];    // 25,344 B
    __shared__ __align__(16) float cmax[3 * SXB];         //  1,584 B
    __shared__ __align__(16) __bf16 sfeat[NK * OW * 32];  // 28,672 B

    const int t  = threadIdx.x;
    const int b  = blockIdx.x >> 6;
    const int ho = blockIdx.x & 63;

    for (int idx = t; idx < Cch * 3 * 32; idx += 256) {
        int c   = idx / 96;
        int rem = idx - c * 96;
        int i   = rem >> 5;
        int q   = rem & 31;
        int r   = 2 * ho - 1 + i;
        v4bf vb = {(__bf16)0.f, (__bf16)0.f, (__bf16)0.f, (__bf16)0.f};
        if (r >= 0 && r < WIMG) {
            float4 v = *(const float4*)(x + (((size_t)(b * Cch + c) * WIMG) + r) * WIMG + q * 4);
            vb = (v4bf){(__bf16)v.x, (__bf16)v.y, (__bf16)v.z, (__bf16)v.w};
        }
        *(v4bf*)(sx + (c * 3 + i) * SXB + 4 * q) = vb;
    }
    if (t < 96) {   // pads: 128,129 (right), 130 (col -1), 131 (unused)
        __bf16* row = sx + t * SXB;
        row[128] = (__bf16)0.f; row[129] = (__bf16)0.f;
        row[130] = (__bf16)0.f; row[131] = (__bf16)0.f;
    }
    __syncthreads();

    if (t < 99) {     // column max over 32 channels (x1 source)
        int i = t / 33, cg = t - i * 33;
        v4bf v0 = *(const v4bf*)(sx + i * SXB + 4 * cg);
        float4 m = make_float4((float)v0.x, (float)v0.y, (float)v0.z, (float)v0.w);
        #pragma unroll 4
        for (int c = 1; c < Cch; ++c) {
            v4bf v = *(const v4bf*)(sx + (c * 3 + i) * SXB + 4 * cg);
            m.x = fmaxf(m.x, (float)v.x); m.y = fmaxf(m.y, (float)v.y);
            m.z = fmaxf(m.z, (float)v.z); m.w = fmaxf(m.w, (float)v.w);
        }
        *(float4*)(cmax + i * SXB + 4 * cg) = m;
    }
    __syncthreads();

    for (int idx = t; idx < 9 * 64; idx += 256) {     // x1
        int f = idx >> 6, wo = idx & 63;
        int i = f / 3, j = f - 3 * i;
        int cc = 2 * wo + j - 1; if (cc < 0) cc = 130;
        sfeat[wo * 32 + f] = (__bf16)cmax[i * SXB + cc];
    }
    {   // x2/x3: thread (wp,g); window cols 4wp-1 .. 4wp+3
        const int wp = t & 31, g = t >> 5;
        const int wo0 = 2 * wp;
        const int lidx = wp ? (4 * wp - 1) : 130;
        #pragma unroll
        for (int cl = 0; cl < 4; ++cl) {
            int c = g * 4 + cl;
            float v[3][5];
            #pragma unroll
            for (int i = 0; i < 3; ++i) {
                const __bf16* row = sx + (c * 3 + i) * SXB;
                v4bf q4 = *(const v4bf*)(row + 4 * wp);
                v[i][1] = (float)q4.x; v[i][2] = (float)q4.y;
                v[i][3] = (float)q4.z; v[i][4] = (float)q4.w;
                v[i][0] = (float)row[lidx];
            }
            #pragma unroll
            for (int i = 0; i < 3; ++i) {            // x3
                int f = 105 + c * 3 + i;
                float a0 = fmaxf(fmaxf(v[i][0], v[i][1]), v[i][2]);
                float a1 = fmaxf(fmaxf(v[i][2], v[i][3]), v[i][4]);
                sfeat[(f >> 5) * 2048 + wo0 * 32 + (f & 31)]       = (__bf16)a0;
                sfeat[(f >> 5) * 2048 + (wo0 + 1) * 32 + (f & 31)] = (__bf16)a1;
            }
            #pragma unroll
            for (int j = 0; j < 3; ++j) {            // x2
                int f = 9 + c * 3 + j;
                float a0 = fmaxf(fmaxf(v[0][j], v[1][j]), v[2][j]);
                float a1 = fmaxf(fmaxf(v[0][j + 2], v[1][j + 2]), v[2][j + 2]);
                sfeat[(f >> 5) * 2048 + wo0 * 32 + (f & 31)]       = (__bf16)a0;
                sfeat[(f >> 5) * 2048 + (wo0 + 1) * 32 + (f & 31)] = (__bf16)a1;
            }
        }
    }
    for (int idx = t; idx < 64 * 23; idx += 256) {   // K padding
        int wo = idx / 23, fo = idx - wo * 23;
        int f = 201 + fo;
        sfeat[6 * 2048 + wo * 32 + (f & 31)] = (__bf16)0.0f;
    }
    __syncthreads();

    const size_t spat0 = (size_t)(b * OH + ho) * OW;
    #pragma unroll
    for (int kc = 0; kc < NK; ++kc) {
        float4 vv = ((const float4*)sfeat)[kc * 256 + t];
        ((float4*)((char*)feat + ((size_t)kc * MTOT + spat0) * 64))[t] = vv;
    }
}

// ---------------------------------------------------------------------------
// K3: gemm v6 = R8 skeleton with the K-loop FULLY UNROLLED (no `unroll 1`):
// the compiler software-pipelines the 7 ksteps (hoists DMA, interleaves
// next-kstep ds_reads under MFMAs with fine lgkmcnt) — the R5 kernel's
// hidden advantage; `#pragma unroll 1` was defeating it in R6-R8.
// Block 384 thr = 6 waves as 2M(64) x 3N(48), tile M=128 x N=144, acc 4x3.
// LDS 37,888 B -> 4 blocks/CU = 24 waves/CU. blockIdx = nb*256+mb (XCD-local A).
// ---------------------------------------------------------------------------
constexpr int YS = 148;   // y row stride (floats)
__global__ __launch_bounds__(384, 4)
void gemm_kernel(const __bf16* __restrict__ feat,
                 const __bf16* __restrict__ Wt,
                 const float* __restrict__ biasp,
                 const float* __restrict__ x,
                 float* __restrict__ out) {
    __shared__ __align__(16) unsigned char lds[64 * YS * 4];  // 37,888 B
    // staging: A dbuf @0 (2 x 8,192), B dbuf @16,384 (2 x 9,216) = 34,816
    // epilogue: y[64][148] fp32 overlays everything

    const int t    = threadIdx.x;
    const int nb   = (int)blockIdx.x >> 8;   // 0..7
    const int mb   = (int)blockIdx.x & 255;  // 0..255
    const int M0   = mb * 128;
    const int N0   = nb * 144;
    const int wave = t >> 6, lane = t & 63, quad = lane >> 4, l16 = lane & 15;
    const int wm   = wave / 3;               // 0..1  (M band of 64)
    const int wn   = wave - 3 * wm;          // 0..2  (N band of 48)

    char* ldsA = (char*)lds;
    char* ldsB = (char*)lds + 16384;

    // 17 DMA segs (8 A + 9 B) distributed over 6 waves
    auto issue = [&](int ks, int buf) {
        const char* Ag = (const char*)feat + ((size_t)ks * MTOT + M0) * 64;
        const char* Bg = (const char*)Wt + ((size_t)ks * OUTCH + N0) * 64;
        #pragma unroll
        for (int i = 0; i < 3; ++i) {
            int seg = wave + 6 * i;
            if (seg < 8) {
                load16_lds(Ag + seg * 1024 + lane * 16,
                           ldsA + buf * 8192 + seg * 1024 + lane * 16);
            } else if (seg < 17) {
                int s = seg - 8;
                load16_lds(Bg + s * 1024 + lane * 16,
                           ldsB + buf * 9216 + s * 1024 + lane * 16);
            }
        }
    };

    v4f acc[4][3];
    #pragma unroll
    for (int mt = 0; mt < 4; ++mt)
        #pragma unroll
        for (int nt = 0; nt < 3; ++nt)
            acc[mt][nt] = (v4f){0.f, 0.f, 0.f, 0.f};

    issue(0, 0);
    __syncthreads();

    #pragma unroll
    for (int ks = 0; ks < NK; ++ks) {
        if (ks + 1 < NK) issue(ks + 1, (ks + 1) & 1);

        const char* Ab = ldsA + (ks & 1) * 8192;
        const char* Bb = ldsB + (ks & 1) * 9216;
        v8bf af[4];
        #pragma unroll
        for (int mt = 0; mt < 4; ++mt)
            af[mt] = *(const v8bf*)(Ab + (wm * 64 + mt * 16 + l16) * 64 + quad * 16);
        v8bf bf[3];
        #pragma unroll
        for (int nt = 0; nt < 3; ++nt)
            bf[nt] = *(const v8bf*)(Bb + (wn * 48 + nt * 16 + l16) * 64 + quad * 16);
        #pragma unroll
        for (int nt = 0; nt < 3; ++nt)
            #pragma unroll
            for (int mt = 0; mt < 4; ++mt)
                acc[mt][nt] = __builtin_amdgcn_mfma_f32_16x16x32_bf16(
                    af[mt], bf[nt], acc[mt][nt], 0, 0, 0);

        __syncthreads();   // publish next chunk; protect dbuf reuse
    }

    // ---- epilogue: two 64-row rounds through shared y[64][148] ----
    float bia[3];
    #pragma unroll
    for (int nt = 0; nt < 3; ++nt)
        bia[nt] = biasp[N0 + wn * 48 + nt * 16 + l16];

    float* y = (float*)lds;
    const float s9 = 1.0f / 9.0f;

    #pragma unroll
    for (int h = 0; h < 2; ++h) {
        if (h) __syncthreads();            // consumers of round 0 done
        if (wm == h) {                     // 3 waves cover all 144 cols
            #pragma unroll
            for (int mt = 0; mt < 4; ++mt)
                #pragma unroll
                for (int nt = 0; nt < 3; ++nt)
                    #pragma unroll
                    for (int r = 0; r < 4; ++r)
                        y[(mt * 16 + quad * 4 + r) * YS + wn * 48 + nt * 16 + l16] =
                            fmaxf(acc[mt][nt][r] + bia[nt], 0.0f);
        }
        __syncthreads();

        // consume: 512 items = 64 rows x 4 ch x 2 halves, over 384 threads
        #pragma unroll
        for (int pass = 0; pass < 2; ++pass) {
            if (pass == 1 && t >= 128) break;
            int item = t + pass * 384;
            int half = item >> 8;          // 0..1 (output sub-row)
            int rem  = item & 255;
            int chl  = rem >> 6;           // 0..3
            int row  = rem & 63;
            int mg   = M0 + h * 64 + row;
            int bb   = mg >> 12;
            int hob  = (mg >> 6) & 63;
            int wo   = mg & 63;
            int cg   = nb * 4 + chl;
            const float* xc = x + (size_t)(bb * Cch + cg) * WIMG * WIMG;

            float pt[9];
            #pragma unroll
            for (int qi = 0; qi < 3; ++qi) {
                int r = 2 * hob - 1 + qi;
                #pragma unroll
                for (int qj = 0; qj < 3; ++qj) {
                    int col = 2 * wo - 1 + qj;
                    float v = 0.0f;
                    if (r >= 0 && r < WIMG && col >= 0 && col < WIMG)
                        v = xc[r * WIMG + col];
                    pt[qi * 3 + qj] = v;
                }
            }
            const float* yr = y + row * YS + chl * 36 + half * 2;
            float o0 = 0.f, o1 = 0.f;
            #pragma unroll
            for (int q = 0; q < 9; ++q) {
                float2 yv = *(const float2*)(yr + q * 4);
                o0 = fmaf(pt[q], yv.x, o0);
                o1 = fmaf(pt[q], yv.y, o1);
            }
            size_t obase = (((size_t)(bb * Cch + cg) * WIMG) + 2 * hob + half) * WIMG + 2 * wo;
            *(float2*)(out + obase) = make_float2(o0 * s9, o1 * s9);
        }
    }
}

extern "C" void kernel_launch(void* const* d_in, const int* in_sizes, int n_in,
                              void* d_out, int out_size, void* d_ws, size_t ws_size,
                              hipStream_t stream) {
    const float* x      = (const float*)d_in[0];
    const float* conv_w = (const float*)d_in[1];
    const float* gamma  = (const float*)d_in[2];
    const float* beta   = (const float*)d_in[3];
    const float* mean   = (const float*)d_in[4];
    const float* var    = (const float*)d_in[5];
    float* out = (float*)d_out;

    __bf16* Wt    = (__bf16*)d_ws;
    float*  biasp = (float*)((char*)d_ws + BIAS_OFF);
    __bf16* feat  = (__bf16*)((char*)d_ws + FEAT_OFF);

    prep_kernel<<<PREP_BLOCKS, 256, 0, stream>>>(conv_w, gamma, beta, mean, var, Wt, biasp);
    feat_kernel<<<FEAT_BLOCKS, 256, 0, stream>>>(x, feat);
    gemm_kernel<<<(OUTCH / 144) * (MTOT / 128), 384, 0, stream>>>(feat, Wt, biasp, x, out);
}

// Round 10
// 124.820 us; speedup vs baseline: 1.0800x; 1.0800x over previous
//
#include <hip/hip_runtime.h>
#include <math.h>

typedef __bf16 v8bf __attribute__((ext_vector_type(8)));
typedef float  v4f  __attribute__((ext_vector_type(4)));

constexpr int Bsz  = 8;
constexpr int Cch  = 32;
constexpr int WIMG = 128;
constexpr int OH   = 64;
constexpr int OW   = 64;
constexpr int INCH = 201;
constexpr int KP   = 224;
constexpr int NK   = 7;
constexpr int OUTCH = 1152;
constexpr int MTOT = Bsz * OH * OW;   // 32768
constexpr float BN_EPS = 1e-5f;

// ws layout
constexpr size_t WT_BYTES = (size_t)NK * OUTCH * 32 * 2;   // 516,096
constexpr size_t BIAS_OFF = WT_BYTES;
constexpr size_t FEAT_OFF = BIAS_OFF + OUTCH * 4;          // 520,704 (16-aligned)

// ---- async global->LDS (wave-uniform base + lane*16 contiguous) ----
typedef const void __attribute__((address_space(1)))* gas_ptr;
typedef void __attribute__((address_space(3)))* las_ptr;
__device__ __forceinline__ void load16_lds(const void* g, void* l) {
    __builtin_amdgcn_global_load_lds((gas_ptr)(uintptr_t)g, (las_ptr)(uintptr_t)l, 16, 0, 0);
}

// ---------------------------------------------------------------------------
// K1: fused prep (blocks >= 512) + feat (blocks 0..511).  (R5-exact)
// ---------------------------------------------------------------------------
constexpr int SXS = 132;            // padded sx row stride (floats)
constexpr int FEAT_BLOCKS = Bsz * OH;        // 512
constexpr int NPREP = OUTCH * KP + OUTCH;    // 259,200
constexpr int PREP_BLOCKS = (NPREP + 255) / 256;

__global__ __launch_bounds__(256)
void prep_feat_kernel(const float* __restrict__ x,
                      const float* __restrict__ conv_w,
                      const float* __restrict__ gamma,
                      const float* __restrict__ beta,
                      const float* __restrict__ mean,
                      const float* __restrict__ var,
                      __bf16* __restrict__ Wt,
                      float* __restrict__ biasp,
                      __bf16* __restrict__ feat) {
    __shared__ __align__(16) float sx[Cch * 3 * SXS];     // 50,688 B
    __shared__ __align__(16) float cmax[3 * SXS];         //  1,584 B
    __shared__ __align__(16) __bf16 sfeat[NK * OW * 32];  // 28,672 B

    const int t = threadIdx.x;

    if (blockIdx.x >= FEAT_BLOCKS) {
        int idx = ((int)blockIdx.x - FEAT_BLOCKS) * 256 + t;
        const int nW = OUTCH * KP;
        if (idx < nW) {
            int o = idx / KP;
            int f = idx - o * KP;
            float inv = gamma[o] * rsqrtf(var[o] + BN_EPS);
            float v = (f < INCH) ? conv_w[o * INCH + f] * inv : 0.0f;
            Wt[((size_t)(f >> 5) * OUTCH + o) * 32 + (f & 31)] = (__bf16)v;
        } else if (idx < nW + OUTCH) {
            int o = idx - nW;
            float inv = gamma[o] * rsqrtf(var[o] + BN_EPS);
            biasp[o] = beta[o] - mean[o] * inv;
        }
        return;
    }

    const int b  = blockIdx.x >> 6;
    const int ho = blockIdx.x & 63;

    for (int idx = t; idx < Cch * 3 * 32; idx += 256) {
        int c   = idx / 96;
        int rem = idx - c * 96;
        int i   = rem >> 5;
        int q   = rem & 31;
        int r   = 2 * ho - 1 + i;
        float4 v = make_float4(0.f, 0.f, 0.f, 0.f);
        if (r >= 0 && r < WIMG)
            v = *(const float4*)(x + (((size_t)(b * Cch + c) * WIMG) + r) * WIMG + q * 4);
        float* dst = sx + (c * 3 + i) * SXS + q * 4 + 1;
        dst[0] = v.x; dst[1] = v.y; dst[2] = v.z; dst[3] = v.w;
    }
    if (t < 96) {
        float* row = sx + t * SXS;
        row[0] = 0.0f; row[129] = 0.0f; row[130] = 0.0f; row[131] = 0.0f;
    }
    __syncthreads();

    if (t < 99) {
        int i = t / 33, cg = t - i * 33;
        const float4* base = (const float4*)sx + i * (SXS / 4) + cg;
        float4 m = base[0];
        #pragma unroll 4
        for (int c = 1; c < Cch; ++c) {
            float4 v = base[(size_t)c * (3 * SXS / 4)];
            m.x = fmaxf(m.x, v.x); m.y = fmaxf(m.y, v.y);
            m.z = fmaxf(m.z, v.z); m.w = fmaxf(m.w, v.w);
        }
        ((float4*)cmax)[i * (SXS / 4) + cg] = m;
    }
    __syncthreads();

    for (int idx = t; idx < 9 * 64; idx += 256) {
        int f = idx >> 6, wo = idx & 63;
        int i = f / 3, j = f - 3 * i;
        sfeat[wo * 32 + f] = (__bf16)cmax[i * SXS + 2 * wo + j];
    }
    {
        const int wp = t & 31, g = t >> 5;
        const int wo0 = 2 * wp;
        #pragma unroll
        for (int cl = 0; cl < 4; ++cl) {
            int c = g * 4 + cl;
            float v[3][5];
            #pragma unroll
            for (int i = 0; i < 3; ++i) {
                const float* row = sx + (c * 3 + i) * SXS + 4 * wp;
                float4 q = *(const float4*)row;
                v[i][0] = q.x; v[i][1] = q.y; v[i][2] = q.z; v[i][3] = q.w;
                v[i][4] = row[4];
            }
            #pragma unroll
            for (int i = 0; i < 3; ++i) {
                int f = 105 + c * 3 + i;
                float a0 = fmaxf(fmaxf(v[i][0], v[i][1]), v[i][2]);
                float a1 = fmaxf(fmaxf(v[i][2], v[i][3]), v[i][4]);
                sfeat[(f >> 5) * 2048 + wo0 * 32 + (f & 31)]       = (__bf16)a0;
                sfeat[(f >> 5) * 2048 + (wo0 + 1) * 32 + (f & 31)] = (__bf16)a1;
            }
            #pragma unroll
            for (int j = 0; j < 3; ++j) {
                int f = 9 + c * 3 + j;
                float a0 = fmaxf(fmaxf(v[0][j], v[1][j]), v[2][j]);
                float a1 = fmaxf(fmaxf(v[0][j + 2], v[1][j + 2]), v[2][j + 2]);
                sfeat[(f >> 5) * 2048 + wo0 * 32 + (f & 31)]       = (__bf16)a0;
                sfeat[(f >> 5) * 2048 + (wo0 + 1) * 32 + (f & 31)] = (__bf16)a1;
            }
        }
    }
    for (int idx = t; idx < 64 * 23; idx += 256) {
        int wo = idx / 23, fo = idx - wo * 23;
        int f = 201 + fo;
        sfeat[6 * 2048 + wo * 32 + (f & 31)] = (__bf16)0.0f;
    }
    __syncthreads();

    const size_t spat0 = (size_t)(b * OH + ho) * OW;
    #pragma unroll
    for (int kc = 0; kc < NK; ++kc) {
        float4 vv = ((const float4*)sfeat)[kc * 256 + t];
        ((float4*)((char*)feat + ((size_t)kc * MTOT + spat0) * 64))[t] = vv;
    }
}

// ---------------------------------------------------------------------------
// K2: gemm v7 = R5's exact skeleton (per-kstep A+B DMA dbuf, 1 barrier/kstep,
// plain K-loop, barrier-free per-wave epilogue) with DEEPER ACC BLOCKING:
// tile M=256 x N=144, 4 waves each M=64 x full-N, acc 4x9.
// LDS-read model (calibrated on m97): reads/kstep/wave 13 b128 (86 cyc) vs
// 36 MFMA (175 cyc) -> MFMA/DMA-bound, vs R5's 11:18 = 3.3x LDS-bound.
// bf single-live inside nt-loop keeps VGPR ~185 (no R2-style spills).
// LDS 51,200 B; epilogue y = 4 private wave regions (37,888 B overlay).
// ---------------------------------------------------------------------------
constexpr int YS  = 148;            // y row stride (floats)
constexpr int REG = 16 * YS;        // per-wave y region (floats) = 9,472 B
__global__ __launch_bounds__(256, 2)
void gemm_kernel(const __bf16* __restrict__ feat,
                 const __bf16* __restrict__ Wt,
                 const float* __restrict__ biasp,
                 const float* __restrict__ x,
                 float* __restrict__ out) {
    __shared__ __align__(16) unsigned char lds[51200];
    // A dbuf @0 (2 x 16,384), B dbuf @32,768 (2 x 9,216); epilogue y @0

    const int t    = threadIdx.x;
    const int nb   = (int)blockIdx.x >> 7;   // 0..7
    const int mb   = (int)blockIdx.x & 127;  // 0..127
    const int M0   = mb * 256;
    const int N0   = nb * 144;
    const int wave = t >> 6, lane = t & 63, quad = lane >> 4, l16 = lane & 15;

    char* ldsA = (char*)lds;
    char* ldsB = (char*)lds + 32768;

    auto issue = [&](int ks, int buf) {
        const char* Ag = (const char*)feat + ((size_t)ks * MTOT + M0) * 64;
        char* Ab = ldsA + buf * 16384;
        #pragma unroll
        for (int i = 0; i < 4; ++i) {
            int off = (wave * 4 + i) * 1024 + lane * 16;
            load16_lds(Ag + off, Ab + off);
        }
        const char* Bg = (const char*)Wt + ((size_t)ks * OUTCH + N0) * 64;
        char* Bb = ldsB + buf * 9216;
        int off0 = wave * 1024 + lane * 16;
        load16_lds(Bg + off0, Bb + off0);
        int off1 = off0 + 4096;
        load16_lds(Bg + off1, Bb + off1);
        if (wave == 0) {
            int off2 = 8192 + lane * 16;
            load16_lds(Bg + off2, Bb + off2);
        }
    };

    v4f acc[4][9];
    #pragma unroll
    for (int mt = 0; mt < 4; ++mt)
        #pragma unroll
        for (int nt = 0; nt < 9; ++nt)
            acc[mt][nt] = (v4f){0.f, 0.f, 0.f, 0.f};

    issue(0, 0);
    __syncthreads();

    for (int ks = 0; ks < NK; ++ks) {
        if (ks + 1 < NK) issue(ks + 1, (ks + 1) & 1);

        const char* Ab = ldsA + (ks & 1) * 16384;
        const char* Bb = ldsB + (ks & 1) * 9216;
        v8bf af[4];
        #pragma unroll
        for (int mt = 0; mt < 4; ++mt)
            af[mt] = *(const v8bf*)(Ab + (wave * 64 + mt * 16 + l16) * 64 + quad * 16);
        #pragma unroll
        for (int nt = 0; nt < 9; ++nt) {
            v8bf bf = *(const v8bf*)(Bb + (nt * 16 + l16) * 64 + quad * 16);
            #pragma unroll
            for (int mt = 0; mt < 4; ++mt)
                acc[mt][nt] = __builtin_amdgcn_mfma_f32_16x16x32_bf16(
                    af[mt], bf, acc[mt][nt], 0, 0, 0);
        }
        __syncthreads();   // publish next chunk; protect dbuf reuse
    }

    // ---- epilogue: per-wave private transpose; no cross-wave barriers ----
    float bia[9];
    #pragma unroll
    for (int nt = 0; nt < 9; ++nt) bia[nt] = biasp[N0 + nt * 16 + l16];

    float* yw = (float*)lds + wave * REG;        // private [16][YS]
    const int cl  = lane >> 4;                   // 0..3 channel-sub
    const int wl  = lane & 15;                   // row within 16-block
    const int cg  = nb * 4 + cl;
    const float s9 = 1.0f / 9.0f;

    #pragma unroll
    for (int p = 0; p < 4; ++p) {
        // produce: M-frag p (rows quad*4+r, cols nt*16+l16)
        #pragma unroll
        for (int nt = 0; nt < 9; ++nt)
            #pragma unroll
            for (int r = 0; r < 4; ++r)
                yw[(quad * 4 + r) * YS + nt * 16 + l16] =
                    fmaxf(acc[p][nt][r] + bia[nt], 0.0f);

        // consume: lane -> global row M0 + wave*64 + p*16 + wl
        const int mg  = M0 + wave * 64 + p * 16 + wl;
        const int bb  = mg >> 12;
        const int hob = (mg >> 6) & 63;
        const int wo  = mg & 63;
        const float* xc = x + (size_t)(bb * Cch + cg) * WIMG * WIMG;

        float pt[9];
        #pragma unroll
        for (int qi = 0; qi < 3; ++qi) {
            int r = 2 * hob - 1 + qi;
            #pragma unroll
            for (int qj = 0; qj < 3; ++qj) {
                int col = 2 * wo - 1 + qj;
                float v = 0.0f;
                if (r >= 0 && r < WIMG && col >= 0 && col < WIMG)
                    v = xc[r * WIMG + col];
                pt[qi * 3 + qj] = v;
            }
        }
        const float4* yrow = (const float4*)(yw + wl * YS + cl * 36);
        float o00 = 0.f, o01 = 0.f, o10 = 0.f, o11 = 0.f;
        #pragma unroll
        for (int q = 0; q < 9; ++q) {
            float4 yv = yrow[q];
            float pq = pt[q];
            o00 = fmaf(pq, yv.x, o00);
            o01 = fmaf(pq, yv.y, o01);
            o10 = fmaf(pq, yv.z, o10);
            o11 = fmaf(pq, yv.w, o11);
        }
        size_t obase = (((size_t)(bb * Cch + cg) * WIMG) + 2 * hob) * WIMG + 2 * wo;
        *(float2*)(out + obase)        = make_float2(o00 * s9, o01 * s9);
        *(float2*)(out + obase + WIMG) = make_float2(o10 * s9, o11 * s9);
    }
}

extern "C" void kernel_launch(void* const* d_in, const int* in_sizes, int n_in,
                              void* d_out, int out_size, void* d_ws, size_t ws_size,
                              hipStream_t stream) {
    const float* x      = (const float*)d_in[0];
    const float* conv_w = (const float*)d_in[1];
    const float* gamma  = (const float*)d_in[2];
    const float* beta   = (const float*)d_in[3];
    const float* mean   = (const float*)d_in[4];
    const float* var    = (const float*)d_in[5];
    float* out = (float*)d_out;

    __bf16* Wt    = (__bf16*)d_ws;
    float*  biasp = (float*)((char*)d_ws + BIAS_OFF);
    __bf16* feat  = (__bf16*)((char*)d_ws + FEAT_OFF);

    prep_feat_kernel<<<FEAT_BLOCKS + PREP_BLOCKS, 256, 0, stream>>>(
        x, conv_w, gamma, beta, mean, var, Wt, biasp, feat);
    gemm_kernel<<<(OUTCH / 144) * (MTOT / 256), 256, 0, stream>>>(feat, Wt, biasp, x, out);
}